// Round 2
// baseline (1297.705 us; speedup 1.0000x reference)
//
#include <hip/hip_runtime.h>
#include <math.h>

#define HH 256
#define WW 256
#define HW (HH*WW)
#define CCH 64

// ---------- tiny transpose: w[O][CK] -> wT[CK][O] ----------
__global__ __launch_bounds__(256) void k_transpose(const float* __restrict__ w,
        float* __restrict__ wT, int O, int CK) {
    int i = blockIdx.x * 256 + threadIdx.x;
    if (i < O * CK) {
        int o = i / CK, ck = i - o * CK;
        wT[ck * O + o] = w[i];
    }
}

// ---------- om = conv3x3(x, w_om) + b_om -> [B,27,H,W] ----------
// blockIdx.y in [0,3): o_base = 9*blockIdx.y
__global__ __launch_bounds__(256) void k_om(const float* __restrict__ x,
        const float* __restrict__ wT, const float* __restrict__ b_om,
        float* __restrict__ om) {
    const int xx = threadIdx.x;
    const int y  = blockIdx.x & (HH - 1);
    const int b  = blockIdx.x >> 8;
    const int ob = blockIdx.y * 9;
    float acc[9];
#pragma unroll
    for (int o = 0; o < 9; ++o) acc[o] = 0.f;
    const float* xb = x + (size_t)b * CCH * HW + y * WW + xx;
#pragma unroll 2
    for (int c = 0; c < CCH; ++c) {
        const float* xc = xb + (size_t)c * HW;
        float v[9];
#pragma unroll
        for (int t = 0; t < 9; ++t) {
            int dy = t / 3 - 1, dx = t % 3 - 1;
            int yy = y + dy, xw = xx + dx;
            bool ok = ((unsigned)yy < HH) && ((unsigned)xw < WW);
            v[t] = ok ? xc[dy * WW + dx] : 0.f;
        }
        const float* wp = wT + c * 9 * 27 + ob;   // uniform address
#pragma unroll
        for (int t = 0; t < 9; ++t)
#pragma unroll
            for (int o = 0; o < 9; ++o)
                acc[o] = fmaf(v[t], wp[t * 27 + o], acc[o]);
    }
    float* op = om + (size_t)b * 27 * HW + (size_t)ob * HW + y * WW + xx;
#pragma unroll
    for (int o = 0; o < 9; ++o) op[(size_t)o * HW] = acc[o] + b_om[ob + o];
}

// ---------- modulated deformable conv + bias + BN1 + ReLU -> h1 ----------
// blockIdx.y in [0,4): o_base = 16*blockIdx.y
__global__ __launch_bounds__(256) void k_dcn(const float* __restrict__ x,
        const float* __restrict__ om, const float* __restrict__ wT,
        const float* __restrict__ bias,
        const float* __restrict__ g, const float* __restrict__ be,
        const float* __restrict__ mu, const float* __restrict__ var,
        float* __restrict__ out) {
    const int xx = threadIdx.x;
    const int y  = blockIdx.x & (HH - 1);
    const int b  = blockIdx.x >> 8;
    const int ob = blockIdx.y * 16;
    float acc[16];
#pragma unroll
    for (int o = 0; o < 16; ++o) acc[o] = 0.f;
    const float* xb  = x + (size_t)b * CCH * HW;
    const float* omp = om + (size_t)b * 27 * HW + y * WW + xx;
    for (int k = 0; k < 9; ++k) {
        const int ky = k / 3 - 1, kx = k % 3 - 1;
        float o1 = omp[(size_t)k * HW];
        float o2 = omp[(size_t)(9 + k) * HW];
        float ml = omp[(size_t)(18 + k) * HW];
        float mask = 1.f / (1.f + expf(-ml));
        float py = (float)(y + ky) + o1;
        float px = (float)(xx + kx) + o2;
        float y0f = floorf(py), x0f = floorf(px);
        float wy1 = py - y0f, wx1 = px - x0f;
        int y0 = (int)y0f, x0i = (int)x0f;
        int y1 = y0 + 1, x1 = x0i + 1;
        float w00 = (1.f - wy1) * (1.f - wx1) * mask;
        float w01 = (1.f - wy1) * wx1 * mask;
        float w10 = wy1 * (1.f - wx1) * mask;
        float w11 = wy1 * wx1 * mask;
        if (!((unsigned)y0  < HH)) { w00 = 0.f; w01 = 0.f; }
        if (!((unsigned)y1  < HH)) { w10 = 0.f; w11 = 0.f; }
        if (!((unsigned)x0i < WW)) { w00 = 0.f; w10 = 0.f; }
        if (!((unsigned)x1  < WW)) { w01 = 0.f; w11 = 0.f; }
        int cy0 = min(max(y0, 0), HH - 1), cy1 = min(max(y1, 0), HH - 1);
        int cx0 = min(max(x0i, 0), WW - 1), cx1 = min(max(x1, 0), WW - 1);
        int i00 = cy0 * WW + cx0, i01 = cy0 * WW + cx1;
        int i10 = cy1 * WW + cx0, i11 = cy1 * WW + cx1;
#pragma unroll 2
        for (int c = 0; c < CCH; ++c) {
            const float* xc = xb + (size_t)c * HW;
            float s = w00 * xc[i00] + w01 * xc[i01] + w10 * xc[i10] + w11 * xc[i11];
            const float* wp = wT + (c * 9 + k) * 64 + ob;   // uniform address
#pragma unroll
            for (int o = 0; o < 16; ++o)
                acc[o] = fmaf(s, wp[o], acc[o]);
        }
    }
    float* hp = out + (size_t)b * CCH * HW + (size_t)ob * HW + y * WW + xx;
#pragma unroll
    for (int o = 0; o < 16; ++o) {
        int oc = ob + o;
        float sc = g[oc] * rsqrtf(var[oc] + 1e-5f);
        float v = (acc[o] + bias[oc] - mu[oc]) * sc + be[oc];
        hp[(size_t)o * HW] = fmaxf(v, 0.f);
    }
}

// ---------- dilated 3x3 conv (dil=2, pad=2) + BN + ReLU ----------
// blockIdx.y in [0,4): o_base = 16*blockIdx.y
__global__ __launch_bounds__(256) void k_conv(const float* __restrict__ in,
        const float* __restrict__ wT, const float* __restrict__ bias,
        const float* __restrict__ g, const float* __restrict__ be,
        const float* __restrict__ mu, const float* __restrict__ var,
        float* __restrict__ out) {
    const int xx = threadIdx.x;
    const int y  = blockIdx.x & (HH - 1);
    const int b  = blockIdx.x >> 8;
    const int ob = blockIdx.y * 16;
    float acc[16];
#pragma unroll
    for (int o = 0; o < 16; ++o) acc[o] = 0.f;
    const float* ib = in + (size_t)b * CCH * HW + y * WW + xx;
#pragma unroll 2
    for (int c = 0; c < CCH; ++c) {
        const float* xc = ib + (size_t)c * HW;
        float v[9];
#pragma unroll
        for (int t = 0; t < 9; ++t) {
            int dy = (t / 3 - 1) * 2, dx = (t % 3 - 1) * 2;
            int yy = y + dy, xw = xx + dx;
            bool ok = ((unsigned)yy < HH) && ((unsigned)xw < WW);
            v[t] = ok ? xc[dy * WW + dx] : 0.f;
        }
        const float* wp = wT + c * 9 * 64 + ob;   // uniform address
#pragma unroll
        for (int t = 0; t < 9; ++t)
#pragma unroll
            for (int o = 0; o < 16; ++o)
                acc[o] = fmaf(v[t], wp[t * 64 + o], acc[o]);
    }
    float* hp = out + (size_t)b * CCH * HW + (size_t)ob * HW + y * WW + xx;
#pragma unroll
    for (int o = 0; o < 16; ++o) {
        int oc = ob + o;
        float sc = g[oc] * rsqrtf(var[oc] + 1e-5f);
        float v = (acc[o] + bias[oc] - mu[oc]) * sc + be[oc];
        hp[(size_t)o * HW] = fmaxf(v, 0.f);
    }
}

// ---------- final 3x3 conv (pad=1, 1 out ch) + sigmoid + clip ----------
__global__ __launch_bounds__(256) void k_final(const float* __restrict__ in,
        const float* __restrict__ w3, const float* __restrict__ b3,
        float* __restrict__ out) {
    const int xx = threadIdx.x;
    const int y  = blockIdx.x & (HH - 1);
    const int b  = blockIdx.x >> 8;
    float acc = 0.f;
    const float* ib = in + (size_t)b * CCH * HW + y * WW + xx;
#pragma unroll 2
    for (int c = 0; c < CCH; ++c) {
        const float* xc = ib + (size_t)c * HW;
        const float* wp = w3 + c * 9;   // w3[0][c][t], uniform
#pragma unroll
        for (int t = 0; t < 9; ++t) {
            int dy = t / 3 - 1, dx = t % 3 - 1;
            int yy = y + dy, xw = xx + dx;
            float v = (((unsigned)yy < HH) && ((unsigned)xw < WW)) ? xc[dy * WW + dx] : 0.f;
            acc = fmaf(v, wp[t], acc);
        }
    }
    float s = 1.f / (1.f + expf(-(acc + b3[0])));
    out[(size_t)b * HW + y * WW + xx] = fminf(fmaxf(s, 1e-4f), 1.f - 1e-4f);
}

extern "C" void kernel_launch(void* const* d_in, const int* in_sizes, int n_in,
                              void* d_out, int out_size, void* d_ws, size_t ws_size,
                              hipStream_t stream) {
    const float* x     = (const float*)d_in[0];
    const float* w_om  = (const float*)d_in[1];
    const float* b_om  = (const float*)d_in[2];
    const float* w_dcn = (const float*)d_in[3];
    const float* b_dcn = (const float*)d_in[4];
    const float* bn1g = (const float*)d_in[5],  *bn1b = (const float*)d_in[6];
    const float* bn1m = (const float*)d_in[7],  *bn1v = (const float*)d_in[8];
    const float* bn2g = (const float*)d_in[9],  *bn2b = (const float*)d_in[10];
    const float* bn2m = (const float*)d_in[11], *bn2v = (const float*)d_in[12];
    const float* bn3g = (const float*)d_in[13], *bn3b = (const float*)d_in[14];
    const float* bn3m = (const float*)d_in[15], *bn3v = (const float*)d_in[16];
    const float* w_h = (const float*)d_in[17], *b_h = (const float*)d_in[18];
    const float* w_w = (const float*)d_in[19], *b_w = (const float*)d_in[20];
    const float* w3  = (const float*)d_in[21], *b3  = (const float*)d_in[22];
    float* outp = (float*)d_out;

    // workspace layout (floats)
    float* ws = (float*)d_ws;
    const size_t OM   = (size_t)2 * 27 * HW;       // 3,538,944
    const size_t HBUF = (size_t)2 * CCH * HW;      // 8,388,608
    float* om    = ws;
    float* h1    = om + OM;
    float* h2    = h1 + HBUF;
    float* wTom  = h2 + HBUF;                      // 27*576
    float* wTdcn = wTom  + 27 * 576;               // 64*576
    float* wTh   = wTdcn + 64 * 576;
    float* wTw   = wTh   + 64 * 576;

    dim3 blk(256);
    k_transpose<<<(27 * 576 + 255) / 256, blk, 0, stream>>>(w_om,  wTom,  27, 576);
    k_transpose<<<(64 * 576 + 255) / 256, blk, 0, stream>>>(w_dcn, wTdcn, 64, 576);
    k_transpose<<<(64 * 576 + 255) / 256, blk, 0, stream>>>(w_h,   wTh,   64, 576);
    k_transpose<<<(64 * 576 + 255) / 256, blk, 0, stream>>>(w_w,   wTw,   64, 576);

    // 512 row-blocks (b,y) x o-splits in blockIdx.y
    k_om  <<<dim3(2 * HH, 3), blk, 0, stream>>>(x, wTom, b_om, om);
    k_dcn <<<dim3(2 * HH, 4), blk, 0, stream>>>(x, om, wTdcn, b_dcn, bn1g, bn1b, bn1m, bn1v, h1);
    k_conv<<<dim3(2 * HH, 4), blk, 0, stream>>>(h1, wTh, b_h, bn2g, bn2b, bn2m, bn2v, h2);
    k_conv<<<dim3(2 * HH, 4), blk, 0, stream>>>(h2, wTw, b_w, bn3g, bn3b, bn3m, bn3v, h1);
    k_final<<<2 * HH, blk, 0, stream>>>(h1, w3, b3, outp);
}

// Round 3
// 469.872 us; speedup vs baseline: 2.7618x; 2.7618x over previous
//
#include <hip/hip_runtime.h>
#include <math.h>

#define HH 256
#define WW 256
#define HW (HH*WW)
#define NPX (2*HW)          // 131072 pixels total

typedef __attribute__((ext_vector_type(8))) short bf16x8;
typedef __attribute__((ext_vector_type(4))) float f32x4;

__device__ __forceinline__ float bf2f(short h) {
    union { unsigned u; float f; } v; v.u = ((unsigned)(unsigned short)h) << 16; return v.f;
}
__device__ __forceinline__ short f2bf(float f) {
    union { float f; unsigned u; } v; v.f = f;
    unsigned r = v.u + 0x7fffu + ((v.u >> 16) & 1u);
    return (short)(r >> 16);
}

// ---------- weight prep: [O][C][3][3] fp32 -> [o][k=t*64+c] bf16 ----------
__global__ __launch_bounds__(256) void k_prep_w(
        const float* __restrict__ w_om, const float* __restrict__ w_dcn,
        const float* __restrict__ w_h,  const float* __restrict__ w_w,
        const float* __restrict__ w3,
        short* __restrict__ wt_om, short* __restrict__ wt_dcn,
        short* __restrict__ wt_h,  short* __restrict__ wt_w,
        float* __restrict__ w3t) {
    int i = blockIdx.x * 256 + threadIdx.x;
    if (i >= 64 * 576) return;
    int o = i / 576, k = i - o * 576, t = k >> 6, c = k & 63;
    int src = (o * 64 + c) * 9 + t;
    wt_dcn[i] = f2bf(w_dcn[src]);
    wt_h[i]   = f2bf(w_h[src]);
    wt_w[i]   = f2bf(w_w[src]);
    if (o < 32) wt_om[o * 576 + k] = (o < 27) ? f2bf(w_om[src]) : (short)0;
    if (o == 0) w3t[k] = w3[c * 9 + t];
}

// ---------- x NCHW fp32 -> channel-last bf16 [B][H][W][64] ----------
__global__ __launch_bounds__(256) void k_x2cl(const float* __restrict__ x,
        short* __restrict__ xcl) {
    __shared__ short tile[256 * 68];
    const int xx = threadIdx.x;
    const int row = blockIdx.x;               // b*256 + y
    const int b = row >> 8, y = row & 255;
    for (int c = 0; c < 64; ++c)
        tile[xx * 68 + c] = f2bf(x[((b * 64 + c) << 16) + (y << 8) + xx]);
    __syncthreads();
    short* op = xcl + ((row << 8) + xx) * 64;
#pragma unroll
    for (int j = 0; j < 8; ++j) {
        bf16x8 v;
#pragma unroll
        for (int e = 0; e < 8; ++e) v[e] = tile[xx * 68 + j * 8 + e];
        *(bf16x8*)(op + j * 8) = v;
    }
}

// ---------- om: implicit GEMM, N=32(27), dil=1 pad=1 -> om_px[px][32] fp32 ----------
__global__ __launch_bounds__(256) void k_om_mfma(const short* __restrict__ xcl,
        const short* __restrict__ wt, const float* __restrict__ b_om,
        float* __restrict__ om_px) {
    const int lane = threadIdx.x & 63, wave = threadIdx.x >> 6;
    const int quad = lane >> 4, l16 = lane & 15;
    const int gpx0 = blockIdx.x * 64 + wave * 16;
    const int x0 = gpx0 & 255, y = (gpx0 >> 8) & 255, b = gpx0 >> 16;
    f32x4 acc[2];
    acc[0] = (f32x4){0,0,0,0}; acc[1] = (f32x4){0,0,0,0};
    const int xA = x0 + l16;
    for (int s = 0; s < 18; ++s) {
        const int t = s >> 1, c0 = (s & 1) * 32;
        const int dy = t / 3 - 1, dx = t % 3 - 1;
        int yy = y + dy, xx = xA + dx;
        bool ok = ((unsigned)yy < 256u) && ((unsigned)xx < 256u);
        int cy = ok ? yy : 0, cx = ok ? xx : 0;
        bf16x8 av = *(const bf16x8*)(xcl + (((b * 256 + cy) * 256 + cx) * 64 + c0 + quad * 8));
        if (!ok) { bf16x8 z = {0,0,0,0,0,0,0,0}; av = z; }
        const int kk = s * 32 + quad * 8;
#pragma unroll
        for (int g = 0; g < 2; ++g) {
            bf16x8 bv = *(const bf16x8*)(wt + (g * 16 + l16) * 576 + kk);
            acc[g] = __builtin_amdgcn_mfma_f32_16x16x32_bf16(av, bv, acc[g], 0, 0, 0);
        }
    }
#pragma unroll
    for (int g = 0; g < 2; ++g) {
        int o = g * 16 + l16;
        float bo = (o < 27) ? b_om[o] : 0.f;
#pragma unroll
        for (int r = 0; r < 4; ++r)
            om_px[(gpx0 + quad * 4 + r) * 32 + o] = acc[g][r] + bo;
    }
}

// ---------- fused modulated deformable conv + BN1 + ReLU -> h_cl bf16 ----------
#define CPXS 328   // LDS px stride (5*64 + 8 pad), 16B aligned
__global__ __launch_bounds__(256) void k_dcn_mfma(const short* __restrict__ xcl,
        const float* __restrict__ om_px, const short* __restrict__ wt,
        const float* __restrict__ bias,
        const float* __restrict__ gg, const float* __restrict__ be,
        const float* __restrict__ mu, const float* __restrict__ var,
        short* __restrict__ out_cl) {
    __shared__ short cols[64 * CPXS];
    const int tid = threadIdx.x;
    const int pl = tid >> 2, q = tid & 3;          // phase-1: pixel-local, ch-quarter
    const int gpx = blockIdx.x * 64 + pl;
    const int x = gpx & 255, y = (gpx >> 8) & 255, b = gpx >> 16;
    const float* omp = om_px + gpx * 32;
    const int lane = tid & 63, wave = tid >> 6;
    const int quad = lane >> 4, l16 = lane & 15;
    const int pxw = wave * 16 + l16;               // phase-2: this lane's A-row pixel
    f32x4 acc[4];
#pragma unroll
    for (int i = 0; i < 4; ++i) acc[i] = (f32x4){0,0,0,0};

    for (int stage = 0; stage < 2; ++stage) {
        const int t0 = stage ? 5 : 0, nt = stage ? 4 : 5;
        const int sbase = stage ? 10 : 0, ns = stage ? 8 : 10;
        if (stage) __syncthreads();                // prior gemm reads done
        // ---- phase 1: build bilinear cols for taps [t0, t0+nt) ----
        for (int tt = 0; tt < nt; ++tt) {
            const int t = t0 + tt;
            const int ky = t / 3 - 1, kx = t % 3 - 1;
            float o1 = omp[t], o2 = omp[9 + t], ml = omp[18 + t];
            float mask = 1.f / (1.f + expf(-ml));
            float py = (float)(y + ky) + o1;
            float px = (float)(x + kx) + o2;
            float y0f = floorf(py), x0f = floorf(px);
            float wy1 = py - y0f, wx1 = px - x0f;
            int y0 = (int)y0f, xi0 = (int)x0f, y1 = y0 + 1, xi1 = xi0 + 1;
            float w00 = (1.f - wy1) * (1.f - wx1) * mask;
            float w01 = (1.f - wy1) * wx1 * mask;
            float w10 = wy1 * (1.f - wx1) * mask;
            float w11 = wy1 * wx1 * mask;
            if (!((unsigned)y0  < 256u)) { w00 = 0.f; w01 = 0.f; }
            if (!((unsigned)y1  < 256u)) { w10 = 0.f; w11 = 0.f; }
            if (!((unsigned)xi0 < 256u)) { w00 = 0.f; w10 = 0.f; }
            if (!((unsigned)xi1 < 256u)) { w01 = 0.f; w11 = 0.f; }
            int cy0 = min(max(y0, 0), 255), cy1 = min(max(y1, 0), 255);
            int cx0 = min(max(xi0, 0), 255), cx1 = min(max(xi1, 0), 255);
            int base = b * 65536;
            int i00 = (base + cy0 * 256 + cx0) * 64;
            int i01 = (base + cy0 * 256 + cx1) * 64;
            int i10 = (base + cy1 * 256 + cx0) * 64;
            int i11 = (base + cy1 * 256 + cx1) * 64;
#pragma unroll
            for (int h = 0; h < 2; ++h) {
                int cb = q * 16 + h * 8;
                bf16x8 a00 = *(const bf16x8*)(xcl + i00 + cb);
                bf16x8 a01 = *(const bf16x8*)(xcl + i01 + cb);
                bf16x8 a10 = *(const bf16x8*)(xcl + i10 + cb);
                bf16x8 a11 = *(const bf16x8*)(xcl + i11 + cb);
                bf16x8 ov;
#pragma unroll
                for (int e = 0; e < 8; ++e) {
                    float s = w00 * bf2f(a00[e]) + w01 * bf2f(a01[e])
                            + w10 * bf2f(a10[e]) + w11 * bf2f(a11[e]);
                    ov[e] = f2bf(s);
                }
                *(bf16x8*)(&cols[pl * CPXS + tt * 64 + cb]) = ov;
            }
        }
        __syncthreads();
        // ---- phase 2: MFMA over this stage's K range ----
        for (int s = 0; s < ns; ++s) {
            const int kl = s * 32 + quad * 8;            // LDS col
            const int kg = (sbase + s) * 32 + quad * 8;  // global k for weights
            bf16x8 av = *(const bf16x8*)(&cols[pxw * CPXS + kl]);
#pragma unroll
            for (int g = 0; g < 4; ++g) {
                bf16x8 bv = *(const bf16x8*)(wt + (g * 16 + l16) * 576 + kg);
                acc[g] = __builtin_amdgcn_mfma_f32_16x16x32_bf16(av, bv, acc[g], 0, 0, 0);
            }
        }
    }
    // epilogue: bias + BN + ReLU -> bf16 channel-last
    const int gpx0 = blockIdx.x * 64 + wave * 16;
#pragma unroll
    for (int g = 0; g < 4; ++g) {
        int o = g * 16 + l16;
        float sc = gg[o] * rsqrtf(var[o] + 1e-5f);
        float off = (bias[o] - mu[o]) * sc + be[o];
#pragma unroll
        for (int r = 0; r < 4; ++r) {
            float v = acc[g][r] * sc + off;
            out_cl[(gpx0 + quad * 4 + r) * 64 + o] = f2bf(fmaxf(v, 0.f));
        }
    }
}

// ---------- dilated conv (dil=2 pad=2) implicit GEMM + BN + ReLU ----------
__global__ __launch_bounds__(256) void k_conv_mfma(const short* __restrict__ in_cl,
        const short* __restrict__ wt, const float* __restrict__ bias,
        const float* __restrict__ gg, const float* __restrict__ be,
        const float* __restrict__ mu, const float* __restrict__ var,
        short* __restrict__ out_cl) {
    const int lane = threadIdx.x & 63, wave = threadIdx.x >> 6;
    const int quad = lane >> 4, l16 = lane & 15;
    const int gpx0 = blockIdx.x * 64 + wave * 16;
    const int x0 = gpx0 & 255, y = (gpx0 >> 8) & 255, b = gpx0 >> 16;
    f32x4 acc[4];
#pragma unroll
    for (int i = 0; i < 4; ++i) acc[i] = (f32x4){0,0,0,0};
    const int xA = x0 + l16;
    for (int s = 0; s < 18; ++s) {
        const int t = s >> 1, c0 = (s & 1) * 32;
        const int dy = (t / 3 - 1) * 2, dx = (t % 3 - 1) * 2;
        int yy = y + dy, xx = xA + dx;
        bool ok = ((unsigned)yy < 256u) && ((unsigned)xx < 256u);
        int cy = ok ? yy : 0, cx = ok ? xx : 0;
        bf16x8 av = *(const bf16x8*)(in_cl + (((b * 256 + cy) * 256 + cx) * 64 + c0 + quad * 8));
        if (!ok) { bf16x8 z = {0,0,0,0,0,0,0,0}; av = z; }
        const int kk = s * 32 + quad * 8;
#pragma unroll
        for (int g = 0; g < 4; ++g) {
            bf16x8 bv = *(const bf16x8*)(wt + (g * 16 + l16) * 576 + kk);
            acc[g] = __builtin_amdgcn_mfma_f32_16x16x32_bf16(av, bv, acc[g], 0, 0, 0);
        }
    }
#pragma unroll
    for (int g = 0; g < 4; ++g) {
        int o = g * 16 + l16;
        float sc = gg[o] * rsqrtf(var[o] + 1e-5f);
        float off = (bias[o] - mu[o]) * sc + be[o];
#pragma unroll
        for (int r = 0; r < 4; ++r) {
            float v = acc[g][r] * sc + off;
            out_cl[(gpx0 + quad * 4 + r) * 64 + o] = f2bf(fmaxf(v, 0.f));
        }
    }
}

// ---------- final 3x3 conv (pad=1, 1 out ch) + sigmoid + clip ----------
__global__ __launch_bounds__(256) void k_final(const short* __restrict__ h_cl,
        const float* __restrict__ w3t, const float* __restrict__ b3,
        float* __restrict__ out) {
    const int gpx = blockIdx.x * 256 + threadIdx.x;
    const int x = gpx & 255, y = (gpx >> 8) & 255, b = gpx >> 16;
    float acc = 0.f;
    for (int t = 0; t < 9; ++t) {
        int yy = y + t / 3 - 1, xx = x + t % 3 - 1;
        if (((unsigned)yy >= 256u) || ((unsigned)xx >= 256u)) continue;
        const short* hp = h_cl + ((b * 256 + yy) * 256 + xx) * 64;
        const float* wp = w3t + t * 64;
#pragma unroll
        for (int j = 0; j < 64; j += 8) {
            bf16x8 v = *(const bf16x8*)(hp + j);
#pragma unroll
            for (int e = 0; e < 8; ++e)
                acc = fmaf(bf2f(v[e]), wp[j + e], acc);
        }
    }
    float s = 1.f / (1.f + expf(-(acc + b3[0])));
    out[gpx] = fminf(fmaxf(s, 1e-4f), 1.f - 1e-4f);
}

extern "C" void kernel_launch(void* const* d_in, const int* in_sizes, int n_in,
                              void* d_out, int out_size, void* d_ws, size_t ws_size,
                              hipStream_t stream) {
    const float* x     = (const float*)d_in[0];
    const float* w_om  = (const float*)d_in[1];
    const float* b_om  = (const float*)d_in[2];
    const float* w_dcn = (const float*)d_in[3];
    const float* b_dcn = (const float*)d_in[4];
    const float* bn1g = (const float*)d_in[5],  *bn1b = (const float*)d_in[6];
    const float* bn1m = (const float*)d_in[7],  *bn1v = (const float*)d_in[8];
    const float* bn2g = (const float*)d_in[9],  *bn2b = (const float*)d_in[10];
    const float* bn2m = (const float*)d_in[11], *bn2v = (const float*)d_in[12];
    const float* bn3g = (const float*)d_in[13], *bn3b = (const float*)d_in[14];
    const float* bn3m = (const float*)d_in[15], *bn3v = (const float*)d_in[16];
    const float* w_h = (const float*)d_in[17], *b_h = (const float*)d_in[18];
    const float* w_w = (const float*)d_in[19], *b_w = (const float*)d_in[20];
    const float* w3  = (const float*)d_in[21], *b3  = (const float*)d_in[22];
    float* outp = (float*)d_out;

    // workspace layout
    char* ws = (char*)d_ws;
    float* om_px = (float*)ws;                         // 131072*32 fp32 = 16.78 MB
    short* xcl   = (short*)(ws + (size_t)NPX * 32 * 4);
    short* h1    = xcl + (size_t)NPX * 64;             // bf16 16.78 MB each
    short* h2    = h1 + (size_t)NPX * 64;
    short* wt_om  = h2 + (size_t)NPX * 64;             // 32*576 bf16
    short* wt_dcn = wt_om  + 32 * 576;                 // 64*576 bf16
    short* wt_h   = wt_dcn + 64 * 576;
    short* wt_w   = wt_h   + 64 * 576;
    float* w3t    = (float*)(wt_w + 64 * 576);         // 576 fp32

    dim3 blk(256);
    k_prep_w<<<(64 * 576 + 255) / 256, blk, 0, stream>>>(
        w_om, w_dcn, w_h, w_w, w3, wt_om, wt_dcn, wt_h, wt_w, w3t);
    k_x2cl<<<512, blk, 0, stream>>>(x, xcl);
    k_om_mfma<<<NPX / 64, blk, 0, stream>>>(xcl, wt_om, b_om, om_px);
    k_dcn_mfma<<<NPX / 64, blk, 0, stream>>>(xcl, om_px, wt_dcn, b_dcn,
                                             bn1g, bn1b, bn1m, bn1v, h1);
    k_conv_mfma<<<NPX / 64, blk, 0, stream>>>(h1, wt_h, b_h, bn2g, bn2b, bn2m, bn2v, h2);
    k_conv_mfma<<<NPX / 64, blk, 0, stream>>>(h2, wt_w, b_w, bn3g, bn3b, bn3m, bn3v, h1);
    k_final<<<512, blk, 0, stream>>>(h1, w3t, b3, outp);
}